// Round 7
// baseline (265.862 us; speedup 1.0000x reference)
//
#include <hip/hip_runtime.h>

#define H 1024
#define HH (H * H)          // 1048576 per channel plane
#define CHW (3 * HH)        // 3145728 per image
#define NB 256
#define HIST_BLOCKS 784

__device__ __forceinline__ float clamp01(float x) { return fminf(fmaxf(x, 0.0f), 1.0f); }

// bin of a value already divided by 255 (v01 = masked_value/255, mask in {0,1})
// (int)(v01*255) is bit-exact vs reference's (int)(clamp01(..)*255*mask).
__device__ __forceinline__ unsigned int bin8(float v01) {
    int b = (int)(v01 * 255.0f);
    return (unsigned int)min(max(b, 0), NB - 1);
}

// ---------------------------------------------------------------------------
// Stage 1: elementwise masking + packed per-pixel bin triples.
// Block 0 additionally zeroes ghist[1536] + counter + flag + loss.
// Plain stores throughout (nt stores measured -6us in R6: they serialize the
// out0/out1 drain instead of letting L3 absorb it under later kernels).
// ---------------------------------------------------------------------------
__global__ void k_elementwise(const float4* __restrict__ inp,
                              const float4* __restrict__ tar,
                              const float4* __restrict__ rfp,
                              const float4* __restrict__ msrc,
                              const float4* __restrict__ mtar,
                              float4* __restrict__ out0, float4* __restrict__ out1,
                              float4* __restrict__ out2, float4* __restrict__ out3,
                              uint4* __restrict__ pk_dst, uint4* __restrict__ pk_ref,
                              unsigned int* __restrict__ gz, float* __restrict__ loss)
{
    if (blockIdx.x == 0) {
        for (int i = threadIdx.x; i < 1538; i += blockDim.x) gz[i] = 0u;  // ghist+counter+flag
        if (threadIdx.x == 0) *loss = 0.0f;
    }
    int p = blockIdx.x * blockDim.x + threadIdx.x;
    if (p >= HH / 4) return;
    float4 ms4 = msrc[p], mt4 = mtar[p];
    // true division: 255.0f/255.0f == 1.0f exactly
    float msx = ms4.x / 255.0f, msy = ms4.y / 255.0f, msz = ms4.z / 255.0f, msw = ms4.w / 255.0f;
    float mtx = mt4.x / 255.0f, mty = mt4.y / 255.0f, mtz = mt4.z / 255.0f, mtw = mt4.w / 255.0f;
    unsigned int bd0 = 0, bd1 = 0, bd2 = 0, bd3 = 0;
    unsigned int br0 = 0, br1 = 0, br2 = 0, br3 = 0;
#pragma unroll
    for (int c = 0; c < 3; ++c) {
        int q = c * (HH / 4) + p;
        float4 t = tar[q], r = rfp[q], iv = inp[q];
        float4 o0, o1, o2;
        o0.x = clamp01((t.x + 1.0f) * 0.5f) * mtx;
        o0.y = clamp01((t.y + 1.0f) * 0.5f) * mty;
        o0.z = clamp01((t.z + 1.0f) * 0.5f) * mtz;
        o0.w = clamp01((t.w + 1.0f) * 0.5f) * mtw;
        o1.x = clamp01((r.x + 1.0f) * 0.5f) * msx;
        o1.y = clamp01((r.y + 1.0f) * 0.5f) * msy;
        o1.z = clamp01((r.z + 1.0f) * 0.5f) * msz;
        o1.w = clamp01((r.w + 1.0f) * 0.5f) * msw;
        o2.x = clamp01(iv.x) * msx;
        o2.y = clamp01(iv.y) * msy;
        o2.z = clamp01(iv.z) * msz;
        o2.w = clamp01(iv.w) * msw;
        out0[q] = o0;
        out1[q] = o1;
        out3[q] = o1;
        out2[q] = o2;
        int sh = 8 * c;
        bd0 |= bin8(o1.x) << sh;  bd1 |= bin8(o1.y) << sh;
        bd2 |= bin8(o1.z) << sh;  bd3 |= bin8(o1.w) << sh;
        br0 |= bin8(o0.x) << sh;  br1 |= bin8(o0.y) << sh;
        br2 |= bin8(o0.z) << sh;  br3 |= bin8(o0.w) << sh;
    }
    pk_dst[p] = make_uint4(bd0, bd1, bd2, bd3);
    pk_ref[p] = make_uint4(br0, br1, br2, br3);
}

// ---------------------------------------------------------------------------
// Stage 2+3+4 fused: histograms -> (last block) cdf+table -> release flag ->
// all blocks scatter. Deadlock-free without co-residency: the flag producer
// is the LAST block to increment the counter, hence already resident/running.
// Cross-XCD safety: table published with atomicExch (device scope), consumed
// with device-scope atomic reads; flag spun on by thread 0 only.
// Scatter-phase pk_dst gathers hit the local L2 warmed by the hist phase.
// ---------------------------------------------------------------------------
__global__ void k_fused(const unsigned int* __restrict__ pk_dst,
                        const unsigned int* __restrict__ pk_ref,
                        const int* __restrict__ i0, const int* __restrict__ i1,
                        const int* __restrict__ i2, const int* __restrict__ i3,
                        unsigned int* __restrict__ ghist, unsigned int* __restrict__ counter,
                        unsigned int* __restrict__ flag, float* __restrict__ table,
                        float* __restrict__ out3, int n)
{
    __shared__ unsigned int h[2 * 3 * NB];
    __shared__ float cdf[6][NB];
    __shared__ float tl[3 * NB];
    __shared__ bool amLast;
    for (int i = threadIdx.x; i < 2 * 3 * NB; i += blockDim.x) h[i] = 0u;
    __syncthreads();

    // ---- hist phase ----
    for (int k = blockIdx.x * blockDim.x + threadIdx.x; k < n; k += gridDim.x * blockDim.x) {
        int pd = i0[k] * H + i1[k];
        int pr = i2[k] * H + i3[k];
        unsigned int a = pk_dst[pd];
        unsigned int b = pk_ref[pr];
        atomicAdd(&h[        (a       & 255u)], 1u);
        atomicAdd(&h[  NB + ((a >> 8) & 255u)], 1u);
        atomicAdd(&h[2*NB + ((a >>16) & 255u)], 1u);
        atomicAdd(&h[3*NB + ( b       & 255u)], 1u);
        atomicAdd(&h[4*NB + ((b >> 8) & 255u)], 1u);
        atomicAdd(&h[5*NB + ((b >>16) & 255u)], 1u);
    }
    __syncthreads();
    for (int i = threadIdx.x; i < 2 * 3 * NB; i += blockDim.x) {
        unsigned int v = h[i];
        if (v) atomicAdd(&ghist[i], v);
    }

    if (threadIdx.x == 0) {
        __threadfence();
        unsigned int old = atomicAdd(counter, 1u);
        amLast = (old == (unsigned int)(gridDim.x - 1));
    }
    __syncthreads();

    // ---- table phase (last block only) ----
    if (amLast) {
        int t = threadIdx.x;
        if (t < 384) {
            int wave = t >> 6, lane = t & 63;
            int base = wave * NB + lane * 4;
            // device-scope atomic reads: see all XCDs' atomicAdds
            unsigned int v0 = atomicAdd(&ghist[base + 0], 0u);
            unsigned int v1 = atomicAdd(&ghist[base + 1], 0u);
            unsigned int v2 = atomicAdd(&ghist[base + 2], 0u);
            unsigned int v3 = atomicAdd(&ghist[base + 3], 0u);
            unsigned int s0 = v0, s1 = s0 + v1, s2 = s1 + v2, s3 = s2 + v3;
            unsigned int scan = s3;
#pragma unroll
            for (int off = 1; off < 64; off <<= 1) {
                unsigned int u = (unsigned int)__shfl_up((int)scan, off, 64);
                if (lane >= off) scan += u;
            }
            unsigned int prefix = scan - s3;
            unsigned int total  = (unsigned int)__shfl((int)scan, 63, 64);
            float ft = (float)total;
            cdf[wave][lane * 4 + 0] = (float)(prefix + s0) / ft;
            cdf[wave][lane * 4 + 1] = (float)(prefix + s1) / ft;
            cdf[wave][lane * 4 + 2] = (float)(prefix + s2) / ft;
            cdf[wave][lane * 4 + 3] = (float)(prefix + s3) / ft;
        }
        __syncthreads();
        if (t < NB) {
#pragma unroll
            for (int c = 0; c < 3; ++c) {
                float r = cdf[c][t];
                const float* cr = cdf[3 + c];
                int lo = 1, hi = NB - 1;
#pragma unroll
                for (int it = 0; it < 8; ++it) {
                    int mid = (lo + hi) >> 1;
                    if (cr[mid] >= r) hi = mid; else lo = mid + 1;
                }
                int jstar = lo - 1;
                int tab = (jstar == 0 && cr[0] > r) ? t : (jstar + 1);
                if (t == NB - 1) tab = NB - 1;
                // device-scope publish (PRE-DIVIDED by 255, the reference's divide)
                atomicExch(&table[c * NB + t], (float)tab / 255.0f);
            }
        }
        __syncthreads();
        if (t == 0) {
            __threadfence();
            atomicExch(flag, 1u);
        }
    }

    // ---- wait for table, stage into LDS ----
    if (threadIdx.x == 0) {
        while (atomicAdd(flag, 0u) == 0u) { __builtin_amdgcn_s_sleep(8); }
    }
    __syncthreads();
    for (int i = threadIdx.x; i < 3 * NB; i += blockDim.x)
        tl[i] = atomicAdd(&table[i], 0.0f);      // device-scope read, bypasses stale L2
    __syncthreads();

    // ---- scatter phase ----
    for (int k = blockIdx.x * blockDim.x + threadIdx.x; k < n; k += gridDim.x * blockDim.x) {
        int pd = i0[k] * H + i1[k];
        unsigned int a = pk_dst[pd];
        out3[         pd] = tl[        (a       & 255u)];
        out3[HH     + pd] = tl[  NB + ((a >> 8) & 255u)];
        out3[2 * HH + pd] = tl[2*NB + ((a >>16) & 255u)];
    }
}

// ---------------------------------------------------------------------------
// Stage 5: loss = mean |out2 - out3| over 3*H*H elements.
// ---------------------------------------------------------------------------
__global__ void k_loss(const float4* __restrict__ a, const float4* __restrict__ b,
                       float* __restrict__ loss)
{
    float s = 0.0f;
    int n4 = CHW / 4;
    for (int i = blockIdx.x * blockDim.x + threadIdx.x; i < n4; i += gridDim.x * blockDim.x) {
        float4 x = a[i], y = b[i];
        s += fabsf(x.x - y.x) + fabsf(x.y - y.y) + fabsf(x.z - y.z) + fabsf(x.w - y.w);
    }
#pragma unroll
    for (int off = 32; off > 0; off >>= 1) s += __shfl_down(s, off);
    __shared__ float ws[4];
    int lane = threadIdx.x & 63, w = threadIdx.x >> 6;
    if (lane == 0) ws[w] = s;
    __syncthreads();
    if (threadIdx.x == 0) {
        float tsum = ws[0] + ws[1] + ws[2] + ws[3];
        atomicAdd(loss, tsum * (1.0f / (float)CHW));
    }
}

extern "C" void kernel_launch(void* const* d_in, const int* in_sizes, int n_in,
                              void* d_out, int out_size, void* d_ws, size_t ws_size,
                              hipStream_t stream)
{
    const float* inp  = (const float*)d_in[0];
    const float* tar  = (const float*)d_in[1];
    const float* rfp  = (const float*)d_in[2];
    const float* msrc = (const float*)d_in[3];
    const float* mtar = (const float*)d_in[4];
    // d_in[5] = target_data_eye (unused by the reference computation)
    const int* i0 = (const int*)d_in[6];
    const int* i1 = (const int*)d_in[7];
    const int* i2 = (const int*)d_in[8];
    const int* i3 = (const int*)d_in[9];
    int n = in_sizes[6];

    float* out0 = (float*)d_out;
    float* out1 = out0 + CHW;
    float* out2 = out1 + CHW;
    float* out3 = out2 + CHW;
    float* loss = out3 + CHW;

    // workspace layout
    unsigned int* ghist   = (unsigned int*)d_ws;                     // [0,6144): 1536 u32
    unsigned int* counter = ghist + 1536;                            // +1 u32
    unsigned int* flag    = ghist + 1537;                            // +1 u32
    float*        table   = (float*)((char*)d_ws + 8192);            // 768 f32
    unsigned int* pk_dst  = (unsigned int*)((char*)d_ws + 16384);    // HH u32 (4 MB)
    unsigned int* pk_ref  = pk_dst + HH;                             // HH u32 (4 MB)

    k_elementwise<<<(HH / 4 + 255) / 256, 256, 0, stream>>>(
        (const float4*)inp, (const float4*)tar, (const float4*)rfp,
        (const float4*)msrc, (const float4*)mtar,
        (float4*)out0, (float4*)out1, (float4*)out2, (float4*)out3,
        (uint4*)pk_dst, (uint4*)pk_ref, ghist, loss);

    k_fused<<<HIST_BLOCKS, 512, 0, stream>>>(pk_dst, pk_ref, i0, i1, i2, i3,
                                             ghist, counter, flag, table, out3, n);

    k_loss<<<768, 256, 0, stream>>>((const float4*)out2, (const float4*)out3, loss);
}

// Round 8
// 199.415 us; speedup vs baseline: 1.3332x; 1.3332x over previous
//
#include <hip/hip_runtime.h>

#define H 1024
#define HH (H * H)          // 1048576 per channel plane
#define CHW (3 * HH)        // 3145728 per image
#define NB 256
#define HIST_BLOCKS 784

__device__ __forceinline__ float clamp01(float x) { return fminf(fmaxf(x, 0.0f), 1.0f); }

// bin of a value already divided by 255 (v01 = masked_value/255, mask in {0,1})
// (int)(v01*255) is bit-exact vs reference's (int)(clamp01(..)*255*mask).
__device__ __forceinline__ unsigned int bin8(float v01) {
    int b = (int)(v01 * 255.0f);
    return (unsigned int)min(max(b, 0), NB - 1);
}

// ---------------------------------------------------------------------------
// Stage 1: elementwise masking + packed per-pixel bin triples.
// Block 0 additionally zeroes ghist[1536] + counter + loss (consumed by later
// kernels; kernel-boundary ordering guarantees visibility).
// Plain stores only: nt stores measured +8us (R6 vs R8) — they force the
// out0/out1 drain to HBM inside this kernel instead of letting L3 absorb it.
// ---------------------------------------------------------------------------
__global__ void k_elementwise(const float4* __restrict__ inp,
                              const float4* __restrict__ tar,
                              const float4* __restrict__ rfp,
                              const float4* __restrict__ msrc,
                              const float4* __restrict__ mtar,
                              float4* __restrict__ out0, float4* __restrict__ out1,
                              float4* __restrict__ out2, float4* __restrict__ out3,
                              uint4* __restrict__ pk_dst, uint4* __restrict__ pk_ref,
                              unsigned int* __restrict__ gz, float* __restrict__ loss)
{
    if (blockIdx.x == 0) {
        for (int i = threadIdx.x; i < 1537; i += blockDim.x) gz[i] = 0u;  // ghist + counter
        if (threadIdx.x == 0) *loss = 0.0f;
    }
    int p = blockIdx.x * blockDim.x + threadIdx.x;
    if (p >= HH / 4) return;
    float4 ms4 = msrc[p], mt4 = mtar[p];
    // true division: 255.0f/255.0f == 1.0f exactly
    float msx = ms4.x / 255.0f, msy = ms4.y / 255.0f, msz = ms4.z / 255.0f, msw = ms4.w / 255.0f;
    float mtx = mt4.x / 255.0f, mty = mt4.y / 255.0f, mtz = mt4.z / 255.0f, mtw = mt4.w / 255.0f;
    unsigned int bd0 = 0, bd1 = 0, bd2 = 0, bd3 = 0;
    unsigned int br0 = 0, br1 = 0, br2 = 0, br3 = 0;
#pragma unroll
    for (int c = 0; c < 3; ++c) {
        int q = c * (HH / 4) + p;
        float4 t = tar[q], r = rfp[q], iv = inp[q];
        float4 o0, o1, o2;
        o0.x = clamp01((t.x + 1.0f) * 0.5f) * mtx;
        o0.y = clamp01((t.y + 1.0f) * 0.5f) * mty;
        o0.z = clamp01((t.z + 1.0f) * 0.5f) * mtz;
        o0.w = clamp01((t.w + 1.0f) * 0.5f) * mtw;
        o1.x = clamp01((r.x + 1.0f) * 0.5f) * msx;
        o1.y = clamp01((r.y + 1.0f) * 0.5f) * msy;
        o1.z = clamp01((r.z + 1.0f) * 0.5f) * msz;
        o1.w = clamp01((r.w + 1.0f) * 0.5f) * msw;
        o2.x = clamp01(iv.x) * msx;
        o2.y = clamp01(iv.y) * msy;
        o2.z = clamp01(iv.z) * msz;
        o2.w = clamp01(iv.w) * msw;
        out0[q] = o0;
        out1[q] = o1;
        out3[q] = o1;
        out2[q] = o2;
        int sh = 8 * c;
        bd0 |= bin8(o1.x) << sh;  bd1 |= bin8(o1.y) << sh;
        bd2 |= bin8(o1.z) << sh;  bd3 |= bin8(o1.w) << sh;
        br0 |= bin8(o0.x) << sh;  br1 |= bin8(o0.y) << sh;
        br2 |= bin8(o0.z) << sh;  br3 |= bin8(o0.w) << sh;
    }
    pk_dst[p] = make_uint4(bd0, bd1, bd2, bd3);
    pk_ref[p] = make_uint4(br0, br1, br2, br3);
}

// ---------------------------------------------------------------------------
// Stage 2+3: histograms from packed bins; LAST block (device-scope counter)
// computes cdfs + transfer table. Table handed to k_scatter across the
// kernel boundary (plain stores — boundary provides ordering/visibility).
// NO intra-kernel grid barrier: R7 measured that pattern at +67us (all
// blocks spin on an L3 atomic line; kernel boundary is far cheaper).
// ---------------------------------------------------------------------------
__global__ void k_hist(const unsigned int* __restrict__ pk_dst,
                       const unsigned int* __restrict__ pk_ref,
                       const int* __restrict__ i0, const int* __restrict__ i1,
                       const int* __restrict__ i2, const int* __restrict__ i3,
                       unsigned int* __restrict__ ghist, unsigned int* __restrict__ counter,
                       float* __restrict__ table, int n)
{
    __shared__ unsigned int h[2 * 3 * NB];
    __shared__ float cdf[6][NB];
    __shared__ bool amLast;
    for (int i = threadIdx.x; i < 2 * 3 * NB; i += blockDim.x) h[i] = 0u;
    __syncthreads();

    for (int k = blockIdx.x * blockDim.x + threadIdx.x; k < n; k += gridDim.x * blockDim.x) {
        int pd = i0[k] * H + i1[k];
        int pr = i2[k] * H + i3[k];
        unsigned int a = pk_dst[pd];
        unsigned int b = pk_ref[pr];
        atomicAdd(&h[        (a       & 255u)], 1u);
        atomicAdd(&h[  NB + ((a >> 8) & 255u)], 1u);
        atomicAdd(&h[2*NB + ((a >>16) & 255u)], 1u);
        atomicAdd(&h[3*NB + ( b       & 255u)], 1u);
        atomicAdd(&h[4*NB + ((b >> 8) & 255u)], 1u);
        atomicAdd(&h[5*NB + ((b >>16) & 255u)], 1u);
    }
    __syncthreads();
    for (int i = threadIdx.x; i < 2 * 3 * NB; i += blockDim.x) {
        unsigned int v = h[i];
        if (v) atomicAdd(&ghist[i], v);
    }

    // completion count; last block computes the tables
    if (threadIdx.x == 0) {
        __threadfence();
        unsigned int old = atomicAdd(counter, 1u);
        amLast = (old == (unsigned int)(gridDim.x - 1));
    }
    __syncthreads();
    if (!amLast) return;

    int t = threadIdx.x;
    if (t < 384) {
        int wave = t >> 6, lane = t & 63;
        int base = wave * NB + lane * 4;
        // device-scope atomic reads: see all XCDs' atomicAdds
        unsigned int v0 = atomicAdd(&ghist[base + 0], 0u);
        unsigned int v1 = atomicAdd(&ghist[base + 1], 0u);
        unsigned int v2 = atomicAdd(&ghist[base + 2], 0u);
        unsigned int v3 = atomicAdd(&ghist[base + 3], 0u);
        unsigned int s0 = v0, s1 = s0 + v1, s2 = s1 + v2, s3 = s2 + v3;
        unsigned int scan = s3;
#pragma unroll
        for (int off = 1; off < 64; off <<= 1) {
            unsigned int u = (unsigned int)__shfl_up((int)scan, off, 64);
            if (lane >= off) scan += u;
        }
        unsigned int prefix = scan - s3;
        unsigned int total  = (unsigned int)__shfl((int)scan, 63, 64);
        float ft = (float)total;
        cdf[wave][lane * 4 + 0] = (float)(prefix + s0) / ft;
        cdf[wave][lane * 4 + 1] = (float)(prefix + s1) / ft;
        cdf[wave][lane * 4 + 2] = (float)(prefix + s2) / ft;
        cdf[wave][lane * 4 + 3] = (float)(prefix + s3) / ft;
    }
    __syncthreads();
    if (t < NB) {
#pragma unroll
        for (int c = 0; c < 3; ++c) {
            float r = cdf[c][t];
            const float* cr = cdf[3 + c];
            int lo = 1, hi = NB - 1;
#pragma unroll
            for (int it = 0; it < 8; ++it) {
                int mid = (lo + hi) >> 1;
                if (cr[mid] >= r) hi = mid; else lo = mid + 1;
            }
            int jstar = lo - 1;
            int tab = (jstar == 0 && cr[0] > r) ? t : (jstar + 1);
            if (t == NB - 1) tab = NB - 1;
            table[c * NB + t] = (float)tab / 255.0f;   // PRE-DIVIDED by 255
        }
    }
}

// ---------------------------------------------------------------------------
// Stage 4: scatter table-mapped values into out3 using packed bins.
// Table staged in LDS. Duplicate pixels write identical values.
// ---------------------------------------------------------------------------
__global__ void k_scatter(const unsigned int* __restrict__ pk_dst,
                          const int* __restrict__ i0, const int* __restrict__ i1,
                          const float* __restrict__ table, float* __restrict__ out3, int n)
{
    __shared__ float tl[3 * NB];
    for (int i = threadIdx.x; i < 3 * NB; i += blockDim.x) tl[i] = table[i];
    __syncthreads();
    int k = blockIdx.x * blockDim.x + threadIdx.x;
    if (k >= n) return;
    int pd = i0[k] * H + i1[k];
    unsigned int a = pk_dst[pd];
    out3[         pd] = tl[        (a       & 255u)];
    out3[HH     + pd] = tl[  NB + ((a >> 8) & 255u)];
    out3[2 * HH + pd] = tl[2*NB + ((a >>16) & 255u)];
}

// ---------------------------------------------------------------------------
// Stage 5: loss = mean |out2 - out3| over 3*H*H elements.
// ---------------------------------------------------------------------------
__global__ void k_loss(const float4* __restrict__ a, const float4* __restrict__ b,
                       float* __restrict__ loss)
{
    float s = 0.0f;
    int n4 = CHW / 4;
    for (int i = blockIdx.x * blockDim.x + threadIdx.x; i < n4; i += gridDim.x * blockDim.x) {
        float4 x = a[i], y = b[i];
        s += fabsf(x.x - y.x) + fabsf(x.y - y.y) + fabsf(x.z - y.z) + fabsf(x.w - y.w);
    }
#pragma unroll
    for (int off = 32; off > 0; off >>= 1) s += __shfl_down(s, off);
    __shared__ float ws[4];
    int lane = threadIdx.x & 63, w = threadIdx.x >> 6;
    if (lane == 0) ws[w] = s;
    __syncthreads();
    if (threadIdx.x == 0) {
        float tsum = ws[0] + ws[1] + ws[2] + ws[3];
        atomicAdd(loss, tsum * (1.0f / (float)CHW));
    }
}

extern "C" void kernel_launch(void* const* d_in, const int* in_sizes, int n_in,
                              void* d_out, int out_size, void* d_ws, size_t ws_size,
                              hipStream_t stream)
{
    const float* inp  = (const float*)d_in[0];
    const float* tar  = (const float*)d_in[1];
    const float* rfp  = (const float*)d_in[2];
    const float* msrc = (const float*)d_in[3];
    const float* mtar = (const float*)d_in[4];
    // d_in[5] = target_data_eye (unused by the reference computation)
    const int* i0 = (const int*)d_in[6];
    const int* i1 = (const int*)d_in[7];
    const int* i2 = (const int*)d_in[8];
    const int* i3 = (const int*)d_in[9];
    int n = in_sizes[6];

    float* out0 = (float*)d_out;
    float* out1 = out0 + CHW;
    float* out2 = out1 + CHW;
    float* out3 = out2 + CHW;
    float* loss = out3 + CHW;

    // workspace layout
    unsigned int* ghist   = (unsigned int*)d_ws;                     // [0,6144): 1536 u32
    unsigned int* counter = ghist + 1536;                            // +1 u32
    float*        table   = (float*)((char*)d_ws + 8192);            // 768 f32
    unsigned int* pk_dst  = (unsigned int*)((char*)d_ws + 16384);    // HH u32 (4 MB)
    unsigned int* pk_ref  = pk_dst + HH;                             // HH u32 (4 MB)

    k_elementwise<<<(HH / 4 + 255) / 256, 256, 0, stream>>>(
        (const float4*)inp, (const float4*)tar, (const float4*)rfp,
        (const float4*)msrc, (const float4*)mtar,
        (float4*)out0, (float4*)out1, (float4*)out2, (float4*)out3,
        (uint4*)pk_dst, (uint4*)pk_ref, ghist, loss);

    k_hist<<<HIST_BLOCKS, 512, 0, stream>>>(pk_dst, pk_ref, i0, i1, i2, i3,
                                            ghist, counter, table, n);

    k_scatter<<<(n + 255) / 256, 256, 0, stream>>>(pk_dst, i0, i1, table, out3, n);

    k_loss<<<768, 256, 0, stream>>>((const float4*)out2, (const float4*)out3, loss);
}

// Round 9
// 188.025 us; speedup vs baseline: 1.4140x; 1.0606x over previous
//
#include <hip/hip_runtime.h>

#define H 1024
#define HH (H * H)          // 1048576 per channel plane
#define CHW (3 * HH)        // 3145728 per image
#define NB 256
#define HIST_BLOCKS 768     // exactly 3 blocks/CU on 256 CUs (784 left 16 CUs with a 4th block: +10us tail)

__device__ __forceinline__ float clamp01(float x) { return fminf(fmaxf(x, 0.0f), 1.0f); }

// bin of a value already divided by 255 (v01 = masked_value/255, mask in {0,1})
// (int)(v01*255) is bit-exact vs reference's (int)(clamp01(..)*255*mask).
__device__ __forceinline__ unsigned int bin8(float v01) {
    int b = (int)(v01 * 255.0f);
    return (unsigned int)min(max(b, 0), NB - 1);
}

// ---------------------------------------------------------------------------
// Stage 1: elementwise masking + packed per-pixel bin triples.
// Block 0 additionally zeroes ghist[1536] + loss (consumed by later kernels;
// kernel-boundary ordering guarantees visibility). Plain stores only
// (nt stores measured neutral-to-negative R6/R8).
// ---------------------------------------------------------------------------
__global__ void k_elementwise(const float4* __restrict__ inp,
                              const float4* __restrict__ tar,
                              const float4* __restrict__ rfp,
                              const float4* __restrict__ msrc,
                              const float4* __restrict__ mtar,
                              float4* __restrict__ out0, float4* __restrict__ out1,
                              float4* __restrict__ out2, float4* __restrict__ out3,
                              uint4* __restrict__ pk_dst, uint4* __restrict__ pk_ref,
                              unsigned int* __restrict__ gz, float* __restrict__ loss)
{
    if (blockIdx.x == 0) {
        for (int i = threadIdx.x; i < 1536; i += blockDim.x) gz[i] = 0u;  // ghist
        if (threadIdx.x == 0) *loss = 0.0f;
    }
    int p = blockIdx.x * blockDim.x + threadIdx.x;
    if (p >= HH / 4) return;
    float4 ms4 = msrc[p], mt4 = mtar[p];
    // true division: 255.0f/255.0f == 1.0f exactly
    float msx = ms4.x / 255.0f, msy = ms4.y / 255.0f, msz = ms4.z / 255.0f, msw = ms4.w / 255.0f;
    float mtx = mt4.x / 255.0f, mty = mt4.y / 255.0f, mtz = mt4.z / 255.0f, mtw = mt4.w / 255.0f;
    unsigned int bd0 = 0, bd1 = 0, bd2 = 0, bd3 = 0;
    unsigned int br0 = 0, br1 = 0, br2 = 0, br3 = 0;
#pragma unroll
    for (int c = 0; c < 3; ++c) {
        int q = c * (HH / 4) + p;
        float4 t = tar[q], r = rfp[q], iv = inp[q];
        float4 o0, o1, o2;
        o0.x = clamp01((t.x + 1.0f) * 0.5f) * mtx;
        o0.y = clamp01((t.y + 1.0f) * 0.5f) * mty;
        o0.z = clamp01((t.z + 1.0f) * 0.5f) * mtz;
        o0.w = clamp01((t.w + 1.0f) * 0.5f) * mtw;
        o1.x = clamp01((r.x + 1.0f) * 0.5f) * msx;
        o1.y = clamp01((r.y + 1.0f) * 0.5f) * msy;
        o1.z = clamp01((r.z + 1.0f) * 0.5f) * msz;
        o1.w = clamp01((r.w + 1.0f) * 0.5f) * msw;
        o2.x = clamp01(iv.x) * msx;
        o2.y = clamp01(iv.y) * msy;
        o2.z = clamp01(iv.z) * msz;
        o2.w = clamp01(iv.w) * msw;
        out0[q] = o0;
        out1[q] = o1;
        out3[q] = o1;
        out2[q] = o2;
        int sh = 8 * c;
        bd0 |= bin8(o1.x) << sh;  bd1 |= bin8(o1.y) << sh;
        bd2 |= bin8(o1.z) << sh;  bd3 |= bin8(o1.w) << sh;
        br0 |= bin8(o0.x) << sh;  br1 |= bin8(o0.y) << sh;
        br2 |= bin8(o0.z) << sh;  br3 |= bin8(o0.w) << sh;
    }
    pk_dst[p] = make_uint4(bd0, bd1, bd2, bd3);
    pk_ref[p] = make_uint4(br0, br1, br2, br3);
}

// ---------------------------------------------------------------------------
// Stage 2: histograms from packed bins. Pure hist — table compute moved back
// to a separate 1-block kernel (R8 measured the last-block fold at +7us: it
// extends k_hist's tail block, which gates k_scatter).
// Ballot aggregation for fully-zero packed values (~30% of samples are
// masked-out -> bins {0,0,0}): one atomicAdd(cnt) per wave instead of up to
// 64 serialized same-address adds. Count semantics identical.
// ---------------------------------------------------------------------------
__global__ void k_hist(const unsigned int* __restrict__ pk_dst,
                       const unsigned int* __restrict__ pk_ref,
                       const int* __restrict__ i0, const int* __restrict__ i1,
                       const int* __restrict__ i2, const int* __restrict__ i3,
                       unsigned int* __restrict__ ghist, int n)
{
    __shared__ unsigned int h[2 * 3 * NB];
    for (int i = threadIdx.x; i < 2 * 3 * NB; i += blockDim.x) h[i] = 0u;
    __syncthreads();

    int lane = threadIdx.x & 63;
    for (int k = blockIdx.x * blockDim.x + threadIdx.x; k < n; k += gridDim.x * blockDim.x) {
        int pd = i0[k] * H + i1[k];
        int pr = i2[k] * H + i3[k];
        unsigned int a = pk_dst[pd];
        unsigned int b = pk_ref[pr];

        unsigned long long mza = __ballot(a == 0u);
        if (a != 0u) {
            atomicAdd(&h[        (a       & 255u)], 1u);
            atomicAdd(&h[  NB + ((a >> 8) & 255u)], 1u);
            atomicAdd(&h[2*NB + ((a >>16) & 255u)], 1u);
        } else if (lane == __ffsll(mza) - 1) {
            unsigned int cnt = (unsigned int)__popcll(mza);
            atomicAdd(&h[0],      cnt);
            atomicAdd(&h[NB],     cnt);
            atomicAdd(&h[2 * NB], cnt);
        }

        unsigned long long mzb = __ballot(b == 0u);
        if (b != 0u) {
            atomicAdd(&h[3*NB + ( b       & 255u)], 1u);
            atomicAdd(&h[4*NB + ((b >> 8) & 255u)], 1u);
            atomicAdd(&h[5*NB + ((b >>16) & 255u)], 1u);
        } else if (lane == __ffsll(mzb) - 1) {
            unsigned int cnt = (unsigned int)__popcll(mzb);
            atomicAdd(&h[3 * NB], cnt);
            atomicAdd(&h[4 * NB], cnt);
            atomicAdd(&h[5 * NB], cnt);
        }
    }
    __syncthreads();
    for (int i = threadIdx.x; i < 2 * 3 * NB; i += blockDim.x) {
        unsigned int v = h[i];
        if (v) atomicAdd(&ghist[i], v);
    }
}

// ---------------------------------------------------------------------------
// Stage 3: cdfs + transfer tables. ONE block of 384 threads = 6 waves.
// Plain uint4 loads of ghist (kernel boundary provides visibility).
// CDF: register scan of 4 -> wave shfl_up scan (integer, bit-exact) ->
// float divide by total. Table: 8-step binary search on monotone cdf_ref
// (identical float comparisons to reference's first-hit linear scan).
// Table stored PRE-DIVIDED by 255 (the reference's single fp divide).
// ---------------------------------------------------------------------------
__global__ void k_tables(const uint4* __restrict__ ghist4, float* __restrict__ table)
{
    __shared__ float cdf[6][NB];     // rows 0-2: cdf_dst, rows 3-5: cdf_ref
    int t = threadIdx.x;
    int wave = t >> 6, lane = t & 63;

    uint4 v = ghist4[wave * 64 + lane];
    unsigned int s0 = v.x;
    unsigned int s1 = s0 + v.y;
    unsigned int s2 = s1 + v.z;
    unsigned int s3 = s2 + v.w;

    unsigned int scan = s3;
#pragma unroll
    for (int off = 1; off < 64; off <<= 1) {
        unsigned int u = (unsigned int)__shfl_up((int)scan, off, 64);
        if (lane >= off) scan += u;
    }
    unsigned int prefix = scan - s3;
    unsigned int total  = (unsigned int)__shfl((int)scan, 63, 64);
    float ft = (float)total;

    cdf[wave][lane * 4 + 0] = (float)(prefix + s0) / ft;
    cdf[wave][lane * 4 + 1] = (float)(prefix + s1) / ft;
    cdf[wave][lane * 4 + 2] = (float)(prefix + s2) / ft;
    cdf[wave][lane * 4 + 3] = (float)(prefix + s3) / ft;
    __syncthreads();

    if (t < NB) {
#pragma unroll
        for (int c = 0; c < 3; ++c) {
            float r = cdf[c][t];
            const float* cr = cdf[3 + c];
            int lo = 1, hi = NB - 1;
#pragma unroll
            for (int it = 0; it < 8; ++it) {
                int mid = (lo + hi) >> 1;
                if (cr[mid] >= r) hi = mid; else lo = mid + 1;
            }
            int jstar = lo - 1;
            int tab = (jstar == 0 && cr[0] > r) ? t : (jstar + 1);
            if (t == NB - 1) tab = NB - 1;
            table[c * NB + t] = (float)tab / 255.0f;   // PRE-DIVIDED by 255
        }
    }
}

// ---------------------------------------------------------------------------
// Stage 4: scatter table-mapped values into out3 using packed bins.
// Table staged in LDS. Duplicate pixels write identical values.
// ---------------------------------------------------------------------------
__global__ void k_scatter(const unsigned int* __restrict__ pk_dst,
                          const int* __restrict__ i0, const int* __restrict__ i1,
                          const float* __restrict__ table, float* __restrict__ out3, int n)
{
    __shared__ float tl[3 * NB];
    for (int i = threadIdx.x; i < 3 * NB; i += blockDim.x) tl[i] = table[i];
    __syncthreads();
    int k = blockIdx.x * blockDim.x + threadIdx.x;
    if (k >= n) return;
    int pd = i0[k] * H + i1[k];
    unsigned int a = pk_dst[pd];
    out3[         pd] = tl[        (a       & 255u)];
    out3[HH     + pd] = tl[  NB + ((a >> 8) & 255u)];
    out3[2 * HH + pd] = tl[2*NB + ((a >>16) & 255u)];
}

// ---------------------------------------------------------------------------
// Stage 5: loss = mean |out2 - out3| over 3*H*H elements.
// ---------------------------------------------------------------------------
__global__ void k_loss(const float4* __restrict__ a, const float4* __restrict__ b,
                       float* __restrict__ loss)
{
    float s = 0.0f;
    int n4 = CHW / 4;
    for (int i = blockIdx.x * blockDim.x + threadIdx.x; i < n4; i += gridDim.x * blockDim.x) {
        float4 x = a[i], y = b[i];
        s += fabsf(x.x - y.x) + fabsf(x.y - y.y) + fabsf(x.z - y.z) + fabsf(x.w - y.w);
    }
#pragma unroll
    for (int off = 32; off > 0; off >>= 1) s += __shfl_down(s, off);
    __shared__ float ws[4];
    int lane = threadIdx.x & 63, w = threadIdx.x >> 6;
    if (lane == 0) ws[w] = s;
    __syncthreads();
    if (threadIdx.x == 0) {
        float tsum = ws[0] + ws[1] + ws[2] + ws[3];
        atomicAdd(loss, tsum * (1.0f / (float)CHW));
    }
}

extern "C" void kernel_launch(void* const* d_in, const int* in_sizes, int n_in,
                              void* d_out, int out_size, void* d_ws, size_t ws_size,
                              hipStream_t stream)
{
    const float* inp  = (const float*)d_in[0];
    const float* tar  = (const float*)d_in[1];
    const float* rfp  = (const float*)d_in[2];
    const float* msrc = (const float*)d_in[3];
    const float* mtar = (const float*)d_in[4];
    // d_in[5] = target_data_eye (unused by the reference computation)
    const int* i0 = (const int*)d_in[6];
    const int* i1 = (const int*)d_in[7];
    const int* i2 = (const int*)d_in[8];
    const int* i3 = (const int*)d_in[9];
    int n = in_sizes[6];

    float* out0 = (float*)d_out;
    float* out1 = out0 + CHW;
    float* out2 = out1 + CHW;
    float* out3 = out2 + CHW;
    float* loss = out3 + CHW;

    // workspace layout
    unsigned int* ghist  = (unsigned int*)d_ws;                     // [0,6144): 1536 u32
    float*        table  = (float*)((char*)d_ws + 8192);            // 768 f32
    unsigned int* pk_dst = (unsigned int*)((char*)d_ws + 16384);    // HH u32 (4 MB)
    unsigned int* pk_ref = pk_dst + HH;                             // HH u32 (4 MB)

    k_elementwise<<<(HH / 4 + 255) / 256, 256, 0, stream>>>(
        (const float4*)inp, (const float4*)tar, (const float4*)rfp,
        (const float4*)msrc, (const float4*)mtar,
        (float4*)out0, (float4*)out1, (float4*)out2, (float4*)out3,
        (uint4*)pk_dst, (uint4*)pk_ref, ghist, loss);

    k_hist<<<HIST_BLOCKS, 512, 0, stream>>>(pk_dst, pk_ref, i0, i1, i2, i3, ghist, n);

    k_tables<<<1, 384, 0, stream>>>((const uint4*)ghist, table);

    k_scatter<<<(n + 255) / 256, 256, 0, stream>>>(pk_dst, i0, i1, table, out3, n);

    k_loss<<<768, 256, 0, stream>>>((const float4*)out2, (const float4*)out3, loss);
}